// Round 9
// baseline (905.441 us; speedup 1.0000x reference)
//
#include <hip/hip_runtime.h>

typedef unsigned long long u64;
typedef __attribute__((ext_vector_type(8))) short s8v;
typedef __attribute__((ext_vector_type(4))) float f4v;

#define VV 110592            // 48^3
#define BB 2
#define NPTS 20000
#define MAXF 5000
#define TPB 192

static inline size_t align_up(size_t v, size_t a){ return (v + a - 1) & ~(a - 1); }

__device__ __forceinline__ int imin(int a, int b){ return a < b ? a : b; }

// round-to-nearest-even f32 -> bf16 bits
__device__ __forceinline__ unsigned rne16(float f){
    unsigned u = __float_as_uint(f);
    return (u + 0x7fffu + ((u >> 16) & 1u)) >> 16;
}
__device__ __forceinline__ float bf2f(unsigned h){ return __uint_as_float(h << 16); }

// ---- software grid barrier: RMW arrival, LOAD spin (no ownership ping-pong) ----
// waits on gridDim.x so it is correct for ANY launched grid size.
__device__ __forceinline__ void gbar(int* cnt)
{
    __syncthreads();
    if (threadIdx.x == 0) {
        __threadfence();                            // release our writes
        atomicAdd(cnt, 1);
        while (__hip_atomic_load(cnt, __ATOMIC_ACQUIRE, __HIP_MEMORY_SCOPE_AGENT) < (int)gridDim.x)
            __builtin_amdgcn_s_sleep(2);
    }
    __syncthreads();
    __threadfence();                                // acquire others' writes
}

struct KP {
    const float* feat; const int* coords;
    const float* w1; const float* w2; const float* w3; const float* w4; const float* w5;
    int* winner; u64* m0; u64* m1; u64* m2;
    int* nout; int* xl5; int* rowbase2;
    short* wpack;
    unsigned short *gHi, *gLo, *aHi, *aLo, *bHi, *bLo;
    float* outf;
    int* bar;
};

// ---------------- conv layer as a device-side phase ----------------
// MODE 0: bf16 hi/lo planes with ReLU + occ-mask.  MODE 1: gathered f32 -> d_out.
template<int MODE>
__device__ void conv_phase(short (*sA)[3][4][400],
        const unsigned short* __restrict__ inHi, const unsigned short* __restrict__ inLo,
        const short* __restrict__ wp, const u64* __restrict__ omask,
        const int* __restrict__ xl5, int xoff,
        unsigned short* __restrict__ outHi, unsigned short* __restrict__ outLo,
        const int* __restrict__ rowbase2, const int* __restrict__ nout,
        float* __restrict__ outf)
{
    const int tid = threadIdx.x;
    const int lane = tid & 63, wv = tid >> 6;          // wv = z-tile 0..2
    const int c4 = lane >> 4, zr = lane & 15;

    for (int rid = blockIdx.x; rid < BB*2304; rid += gridDim.x) {
        int b = rid / 2304, r = rid - b*2304, x = r / 48, y = r - x*48;
        int lim = imin(47, xl5[b] + xoff);
        if (x > lim) continue;                          // block-uniform

        f4v acc0 = {0.f,0.f,0.f,0.f};
        f4v acc1 = {0.f,0.f,0.f,0.f};
        const size_t inb = (size_t)b*VV*32;

        for (int dx = 0; dx < 3; ++dx) {
            __syncthreads();
            int xx = x + dx - 1;
            if ((unsigned)xx >= 48u) continue;
            // stage 3 y-rows (hi+lo), transposed [cichunk][z], z padded with zeros
            for (int e = tid; e < 1200; e += TPB) {
                int z = e % 50;
                int rr = e / 50;
                int c = rr & 3; rr >>= 2;
                int dy = rr % 3, pl = rr / 3;
                int yy = y + dy - 1, zz = z - 1;
                s8v v = {0,0,0,0,0,0,0,0};
                if ((unsigned)yy < 48u && (unsigned)zz < 48u) {
                    const unsigned short* src = (pl ? inLo : inHi) + inb
                        + ((size_t)((xx*48 + yy)*48 + zz)*32 + c*8);
                    v = *(const s8v*)src;
                }
                *(s8v*)&sA[pl][dy][c][z*8] = v;
            }
            __syncthreads();
            for (int dy = 0; dy < 3; ++dy) {
                #pragma unroll
                for (int dz = 0; dz < 3; ++dz) {
                    s8v Ah = *(const s8v*)&sA[0][dy][c4][(wv*16 + zr + dz)*8];
                    s8v Al = *(const s8v*)&sA[1][dy][c4][(wv*16 + zr + dz)*8];
                    int tap = (dx*3 + dy)*3 + dz;
                    const s8v* wb = (const s8v*)(wp + (size_t)tap*2048);
                    s8v Bh0 = wb[0*64 + lane];
                    s8v Bl0 = wb[1*64 + lane];
                    s8v Bh1 = wb[2*64 + lane];
                    s8v Bl1 = wb[3*64 + lane];
                    acc0 = __builtin_amdgcn_mfma_f32_16x16x32_bf16(Ah, Bh0, acc0, 0, 0, 0);
                    acc1 = __builtin_amdgcn_mfma_f32_16x16x32_bf16(Ah, Bh1, acc1, 0, 0, 0);
                    acc0 = __builtin_amdgcn_mfma_f32_16x16x32_bf16(Ah, Bl0, acc0, 0, 0, 0);
                    acc1 = __builtin_amdgcn_mfma_f32_16x16x32_bf16(Ah, Bl1, acc1, 0, 0, 0);
                    acc0 = __builtin_amdgcn_mfma_f32_16x16x32_bf16(Al, Bh0, acc0, 0, 0, 0);
                    acc1 = __builtin_amdgcn_mfma_f32_16x16x32_bf16(Al, Bh1, acc1, 0, 0, 0);
                }
            }
        }

        // epilogue: D layout col = lane&15, row = (lane>>4)*4 + reg
        u64 om = omask[b*2304 + x*48 + y];
        int co_l = lane & 15, rg = lane >> 4;
        if (MODE == 0) {
            #pragma unroll
            for (int half = 0; half < 2; ++half) {
                f4v a = half ? acc1 : acc0;
                #pragma unroll
                for (int reg = 0; reg < 4; ++reg) {
                    int z = wv*16 + rg*4 + reg;
                    float v = fmaxf(a[reg], 0.f);
                    if (!((om >> z) & 1ull)) v = 0.f;
                    unsigned hb = rne16(v);
                    unsigned lb = rne16(v - bf2f(hb));
                    size_t o = inb + ((size_t)((x*48 + y)*48 + z))*32 + half*16 + co_l;
                    outHi[o] = (unsigned short)hb;
                    outLo[o] = (unsigned short)lb;
                }
            }
        } else {
            int nb_ = imin(nout[b], MAXF);
            int rb = rowbase2[(b*48 + x)*48 + y];
            #pragma unroll
            for (int half = 0; half < 2; ++half) {
                f4v a = half ? acc1 : acc0;
                #pragma unroll
                for (int reg = 0; reg < 4; ++reg) {
                    int z = wv*16 + rg*4 + reg;
                    if ((om >> z) & 1ull) {
                        int rank = __popcll(om & ((1ull << z) - 1ull));
                        int slot = rb + rank;
                        if (slot >= 0 && slot < nb_)
                            outf[((size_t)(b*MAXF + slot))*32 + half*16 + co_l] = a[reg];
                    }
                }
            }
        }
    }
}

// ---------------- the whole pipeline as one plain kernel + software barriers ----------------
__global__ __launch_bounds__(TPB, 2) void fused_k(KP p)
{
    __shared__ short sA[2][3][4][400];     // 19.2 KB conv staging
    __shared__ int st_c2[96];
    __shared__ int st_sb[96];

    const int tid = threadIdx.x;
    const int gt  = blockIdx.x*TPB + tid;
    const int GT  = gridDim.x*TPB;

    // ---- A: init (winner=-1, m0=0, out=0, grid planes=0) ----
    {
        s8v z8 = {0,0,0,0,0,0,0,0};
        const int NC = BB*VV*32/8;                      // s8v chunks per plane
        for (int i = gt; i < NC; i += GT) {
            *(s8v*)&p.gHi[(size_t)i*8] = z8;
            *(s8v*)&p.gLo[(size_t)i*8] = z8;
        }
        for (int i = gt; i < BB*VV; i += GT) p.winner[i] = -1;
        for (int i = gt; i < BB*2304; i += GT) p.m0[i] = 0;
        f4v zf = {0.f,0.f,0.f,0.f};
        for (int i = gt; i < BB*MAXF*8; i += GT) *(f4v*)&p.outf[(size_t)i*4] = zf;
    }
    gbar(p.bar + 0);

    // ---- B: scatter pass 1 (winner + occupancy bitmask) ----
    for (int t = gt; t < BB*NPTS; t += GT) {
        int b = t / NPTS, n = t - b*NPTS;
        const int* c = p.coords + (size_t)t*3;
        atomicMax(&p.winner[b*VV + (c[0]*48 + c[1])*48 + c[2]], n);
        atomicOr(&p.m0[b*2304 + c[0]*48 + c[1]], 1ull << c[2]);
    }
    gbar(p.bar + 1);

    // ---- C: dilations (r=1 and r=2 direct from m0) + weight pack ----
    for (int t = gt; t < BB*2304; t += GT) {
        int b = t / 2304, r = t - b*2304, x = r / 48, y = r - x*48;
        u64 a1 = 0, a2 = 0;
        for (int dx=-2; dx<=2; ++dx){ int xx=x+dx; if ((unsigned)xx >= 48u) continue;
          for (int dy=-2; dy<=2; ++dy){ int yy=y+dy; if ((unsigned)yy >= 48u) continue;
            u64 m = p.m0[b*2304 + xx*48 + yy];
            u64 d1 = m | (m<<1) | (m>>1);
            a2 |= d1 | (m<<2) | (m>>2);
            if (dx>=-1 && dx<=1 && dy>=-1 && dy<=1) a1 |= d1;
          }}
        p.m1[t] = a1 & ((1ull<<48) - 1ull);
        p.m2[t] = a2 & ((1ull<<48) - 1ull);
    }
    for (int t = gt; t < 270*64; t += GT) {
        int lane = t & 63, bid = t >> 6;
        int layer = bid / 54; int r = bid % 54; int tap = r >> 1, half = r & 1;
        const float* w = layer==0?p.w1: layer==1?p.w2: layer==2?p.w3: layer==3?p.w4: p.w5;
        int cin = (layer == 0) ? 16 : 32;
        int n = half*16 + (lane & 15);
        s8v hv, lv;
        #pragma unroll
        for (int j = 0; j < 8; ++j) {
            int k = (lane >> 4)*8 + j;
            float v = (k < cin) ? w[((size_t)tap*cin + k)*32 + n] : 0.f;
            unsigned hb = rne16(v);
            hv[j] = (short)hb;
            lv[j] = (short)rne16(v - bf2f(hb));
        }
        size_t base = ((size_t)(layer*27 + tap)*2 + half)*2*512 + (size_t)(lane)*8;
        *(s8v*)&p.wpack[base] = hv;
        *(s8v*)&p.wpack[base + 512] = lv;
    }
    gbar(p.bar + 2);

    // ---- D: stats (block 0) + winner-only feature scatter (other blocks) ----
    if (blockIdx.x == 0) {
        if (tid < 96) {
            int s = 0;
            for (int y = 0; y < 48; ++y) s += __popcll(p.m2[tid*48 + y]);
            st_c2[tid] = s;
        }
        __syncthreads();
        if (tid < BB) {
            int b = tid, run = 0, xl = 0;
            int cum[48];
            for (int x = 0; x < 48; ++x) { st_sb[b*48+x] = run; run += st_c2[b*48+x]; cum[x] = run; }
            int nsel = run < MAXF ? run : MAXF;
            for (int x = 0; x < 48; ++x) { if (cum[x] >= nsel) { xl = x; break; } }
            if (nsel == 0) xl = 0;
            p.nout[b] = nsel; p.xl5[b] = xl;
        }
        __syncthreads();
        if (tid < 96) {
            int run = st_sb[tid];
            for (int y = 0; y < 48; ++y) {
                p.rowbase2[tid*48 + y] = run;
                run += __popcll(p.m2[tid*48 + y]);
            }
        }
    } else {
        for (int t = (blockIdx.x-1)*TPB + tid; t < BB*NPTS; t += (gridDim.x-1)*TPB) {
            int b = t / NPTS, n = t - b*NPTS;
            const int* c = p.coords + (size_t)t*3;
            int gi = b*VV + (c[0]*48 + c[1])*48 + c[2];
            if (p.winner[gi] != n) continue;
            const float* f = p.feat + (size_t)t*16;
            size_t base = (size_t)gi*32;
            #pragma unroll
            for (int ch = 0; ch < 2; ++ch) {
                s8v hv, lv;
                #pragma unroll
                for (int j = 0; j < 8; ++j) {
                    float v = f[ch*8 + j];
                    unsigned hb = rne16(v);
                    hv[j] = (short)hb;
                    lv[j] = (short)rne16(v - bf2f(hb));
                }
                *(s8v*)&p.gHi[base + ch*8] = hv;
                *(s8v*)&p.gLo[base + ch*8] = lv;
            }
        }
    }
    gbar(p.bar + 3);

    // ---- conv chain ----
    const size_t LSZ = (size_t)27*2048;    // shorts per layer in wpack
    conv_phase<0>(sA, p.gHi, p.gLo, p.wpack + 0*LSZ, p.m0, p.xl5, 4,
                  p.aHi, p.aLo, nullptr, nullptr, nullptr);
    gbar(p.bar + 4);
    conv_phase<0>(sA, p.aHi, p.aLo, p.wpack + 1*LSZ, p.m0, p.xl5, 3,
                  p.bHi, p.bLo, nullptr, nullptr, nullptr);
    gbar(p.bar + 5);
    conv_phase<0>(sA, p.bHi, p.bLo, p.wpack + 2*LSZ, p.m0, p.xl5, 2,
                  p.aHi, p.aLo, nullptr, nullptr, nullptr);
    gbar(p.bar + 6);
    conv_phase<0>(sA, p.aHi, p.aLo, p.wpack + 3*LSZ, p.m1, p.xl5, 1,
                  p.bHi, p.bLo, nullptr, nullptr, nullptr);
    gbar(p.bar + 7);
    conv_phase<1>(sA, p.bHi, p.bLo, p.wpack + 4*LSZ, p.m2, p.xl5, 0,
                  nullptr, nullptr, p.rowbase2, p.nout, p.outf);
}

extern "C" void kernel_launch(void* const* d_in, const int* in_sizes, int n_in,
                              void* d_out, int out_size, void* d_ws, size_t ws_size,
                              hipStream_t stream)
{
    (void)in_sizes; (void)n_in; (void)out_size; (void)ws_size;

    char* ws = (char*)d_ws;
    size_t off = 0;
    auto carve = [&](size_t bytes)->char* { char* p = ws + off; off = align_up(off + bytes, 256); return p; };

    KP kp;
    kp.feat   = (const float*)d_in[0];
    kp.coords = (const int*)d_in[1];
    kp.w1 = (const float*)d_in[2];
    kp.w2 = (const float*)d_in[3];
    kp.w3 = (const float*)d_in[4];
    kp.w4 = (const float*)d_in[5];
    kp.w5 = (const float*)d_in[6];
    kp.outf = (float*)d_out;

    kp.winner   = (int*)carve((size_t)BB*VV*4);
    kp.m0       = (u64*)carve((size_t)BB*2304*8);
    kp.m1       = (u64*)carve((size_t)BB*2304*8);
    kp.m2       = (u64*)carve((size_t)BB*2304*8);
    kp.nout     = (int*)carve(BB*4);
    kp.xl5      = (int*)carve(BB*4);
    kp.rowbase2 = (int*)carve(96*48*4);
    kp.wpack    = (short*)carve((size_t)5*27*2048*2);
    kp.gHi      = (unsigned short*)carve((size_t)BB*VV*32*2);
    kp.gLo      = (unsigned short*)carve((size_t)BB*VV*32*2);
    kp.aHi      = (unsigned short*)carve((size_t)BB*VV*32*2);
    kp.aLo      = (unsigned short*)carve((size_t)BB*VV*32*2);
    kp.bHi      = (unsigned short*)carve((size_t)BB*VV*32*2);
    kp.bLo      = (unsigned short*)carve((size_t)BB*VV*32*2);
    kp.bar      = (int*)carve(16*4);

    // Deadlock-proof grid size: ask the runtime how many blocks/CU actually fit
    // (host-side computation; capture-legal; deterministic per call).
    int maxb = 0;
    hipError_t oe = hipOccupancyMaxActiveBlocksPerMultiprocessor(&maxb, fused_k, TPB, 0);
    if (oe != hipSuccess || maxb < 1) maxb = 1;
    int grid = maxb * 256;
    if (grid > 1024) grid = 1024;

    hipMemsetAsync(kp.bar, 0, 16*4, stream);
    fused_k<<<dim3(grid), dim3(TPB), 0, stream>>>(kp);
}

// Round 10
// 201.727 us; speedup vs baseline: 4.4884x; 4.4884x over previous
//
#include <hip/hip_runtime.h>

typedef unsigned long long u64;
typedef __attribute__((ext_vector_type(8))) short s8v;
typedef __attribute__((ext_vector_type(4))) float f4v;

#define VV 110592            // 48^3
#define BB 2
#define NPTS 20000
#define MAXF 5000

static inline size_t align_up(size_t v, size_t a){ return (v + a - 1) & ~(a - 1); }

__device__ __forceinline__ int imin(int a, int b){ return a < b ? a : b; }

// round-to-nearest-even f32 -> bf16 bits
__device__ __forceinline__ unsigned rne16(float f){
    unsigned u = __float_as_uint(f);
    return (u + 0x7fffu + ((u >> 16) & 1u)) >> 16;
}
__device__ __forceinline__ float bf2f(unsigned h){ return __uint_as_float(h << 16); }

// ---------------- K1: scatter pass 1 (winner+mask) + weight pack ----------------
// blocks [0,209): scatter points; blocks [209,299): pack 270 (layer,tap,half) groups.
__global__ __launch_bounds__(192) void k1_scatter_wpack(
        const int* __restrict__ coords,
        const float* __restrict__ w1, const float* __restrict__ w2,
        const float* __restrict__ w3, const float* __restrict__ w4,
        const float* __restrict__ w5,
        int* __restrict__ winner, u64* __restrict__ m0, short* __restrict__ wpack)
{
    int bid = blockIdx.x;
    if (bid < 209) {
        int t = bid*192 + threadIdx.x;
        if (t >= BB*NPTS) return;
        int b = t / NPTS, n = t - b*NPTS;
        const int* c = coords + (size_t)t*3;
        atomicMax(&winner[b*VV + (c[0]*48 + c[1])*48 + c[2]], n);
        atomicOr(&m0[b*2304 + c[0]*48 + c[1]], 1ull << c[2]);
    } else {
        int g = (bid - 209)*192 + threadIdx.x;    // 0..17279 = 270 groups * 64 lanes
        int lane = g & 63, wb = g >> 6;
        int layer = wb / 54; int r = wb % 54; int tap = r >> 1, half = r & 1;
        const float* w = layer==0?w1: layer==1?w2: layer==2?w3: layer==3?w4: w5;
        int cin = (layer == 0) ? 16 : 32;
        int n = half*16 + (lane & 15);
        s8v hv, lv;
        #pragma unroll
        for (int j = 0; j < 8; ++j) {
            int k = (lane >> 4)*8 + j;
            float v = (k < cin) ? w[((size_t)tap*cin + k)*32 + n] : 0.f;
            unsigned hb = rne16(v);
            hv[j] = (short)hb;
            lv[j] = (short)rne16(v - bf2f(hb));
        }
        size_t base = ((size_t)(layer*27 + tap)*2 + half)*2*512 + (size_t)lane*8;
        *(s8v*)&wpack[base] = hv;
        *(s8v*)&wpack[base + 512] = lv;
    }
}

// ---------------- K2: single-block stats (m2 on the fly) -> xl5, nout, rowbase2 ----------------
__global__ __launch_bounds__(1024) void k2_stats(const u64* __restrict__ m0,
        int* __restrict__ nout, int* __restrict__ xl5, int* __restrict__ rowbase2)
{
    __shared__ int cnt[BB*2304];
    __shared__ int sliceTot[96], sliceBase[96];
    int tid = threadIdx.x;
    for (int rid = tid; rid < BB*2304; rid += 1024) {
        int b = rid / 2304, r = rid - b*2304, x = r / 48, y = r - x*48;
        u64 a2 = 0;
        for (int dx=-2; dx<=2; ++dx){ int xx=x+dx; if ((unsigned)xx >= 48u) continue;
          for (int dy=-2; dy<=2; ++dy){ int yy=y+dy; if ((unsigned)yy >= 48u) continue;
            u64 m = m0[b*2304 + xx*48 + yy];
            a2 |= m | (m<<1) | (m>>1) | (m<<2) | (m>>2);
          }}
        cnt[rid] = __popcll(a2 & ((1ull<<48) - 1ull));
    }
    __syncthreads();
    if (tid < 96) { int s = 0; for (int y=0;y<48;++y) s += cnt[tid*48+y]; sliceTot[tid] = s; }
    __syncthreads();
    if (tid < BB) {
        int b = tid;
        int tot = 0; for (int x=0;x<48;++x) tot += sliceTot[b*48+x];
        int nsel = tot < MAXF ? tot : MAXF;
        int run = 0;
        for (int x=0;x<48;++x){ sliceBase[b*48+x] = run; run += sliceTot[b*48+x]; }
        int cum = 0, xl = 0;
        for (int x=0;x<48;++x){ cum += sliceTot[b*48+x]; if (cum >= nsel){ xl = x; break; } }
        if (nsel == 0) xl = 0;
        nout[b] = nsel; xl5[b] = xl;
    }
    __syncthreads();
    if (tid < 96) {
        int run = sliceBase[tid];
        for (int y=0;y<48;++y){ rowbase2[tid*48+y] = run; run += cnt[tid*48+y]; }
    }
}

// ---------------- K3: masked slab zero (non-occupied voxels) + winner feature scatter ----------------
__global__ __launch_bounds__(192) void k3_zero_scatter(
        const int* __restrict__ coords, const float* __restrict__ feat,
        const int* __restrict__ winner, const u64* __restrict__ m0,
        const int* __restrict__ xl5,
        unsigned short* __restrict__ gHi, unsigned short* __restrict__ gLo)
{
    int bid = blockIdx.x;
    if (bid < BB*2304) {
        int b = bid / 2304, r = bid - b*2304, x = r / 48, y = r - x*48;
        if (x > imin(47, xl5[b] + 5)) return;
        u64 om = m0[b*2304 + x*48 + y];
        int i = threadIdx.x;                 // chunk 0..191, z = i>>2
        int z = i >> 2;
        if (!((om >> z) & 1ull)) {
            size_t base = ((size_t)b*VV + x*2304 + y*48) * 32 + (size_t)i*8;
            s8v z8 = {0,0,0,0,0,0,0,0};
            *(s8v*)&gHi[base] = z8;
            *(s8v*)&gLo[base] = z8;
        }
    } else {
        int t = (bid - BB*2304)*192 + threadIdx.x;
        if (t >= BB*NPTS) return;
        int b = t / NPTS, n = t - b*NPTS;
        const int* c = coords + (size_t)t*3;
        int gi = b*VV + (c[0]*48 + c[1])*48 + c[2];
        if (winner[gi] != n) return;
        const float* f = feat + (size_t)t*16;
        size_t base = (size_t)gi*32;
        #pragma unroll
        for (int ch = 0; ch < 2; ++ch) {
            s8v hv, lv;
            #pragma unroll
            for (int j = 0; j < 8; ++j) {
                float v = f[ch*8 + j];
                unsigned hb = rne16(v);
                hv[j] = (short)hb;
                lv[j] = (short)rne16(v - bf2f(hb));
            }
            *(s8v*)&gHi[base + ch*8] = hv;
            *(s8v*)&gLo[base + ch*8] = lv;
        }
    }
}

// ---------------- MFMA conv layer (round-4 proven body; mask computed on the fly) ----------------
// MODE 0: write bf16 hi/lo planes with ReLU + mask.  MODE 1: gathered f32 -> d_out.
// DIL: epilogue mask = m0 dilated by DIL (0: m0, 1: m1, 2: m2).
template<int MODE, int DIL>
__global__ __launch_bounds__(192) void conv_mfma_k(
        const unsigned short* __restrict__ inHi, const unsigned short* __restrict__ inLo,
        const short* __restrict__ wp, const u64* __restrict__ m0,
        const int* __restrict__ xl5, int xoff,
        unsigned short* __restrict__ outHi, unsigned short* __restrict__ outLo,
        const int* __restrict__ rowbase2, const int* __restrict__ nout,
        float* __restrict__ outf)
{
    int y = blockIdx.x, x = blockIdx.y, b = blockIdx.z;
    int lim = imin(47, xl5[b] + xoff);
    if (x > lim) return;

    __shared__ short sA[2][3][4][400];   // [plane][dy][cichunk][50 z * 8 bf16] = 19.2 KB
    int tid = threadIdx.x;
    int lane = tid & 63;
    int wv = tid >> 6;                   // z-tile 0..2
    int c4 = lane >> 4, zr = lane & 15;

    f4v acc0 = {0.f,0.f,0.f,0.f};
    f4v acc1 = {0.f,0.f,0.f,0.f};
    const size_t inb = (size_t)b*VV*32;

    for (int dx = 0; dx < 3; ++dx) {
        __syncthreads();
        int xx = x + dx - 1;
        if ((unsigned)xx >= 48u) continue;
        for (int e = tid; e < 1200; e += 192) {
            int z = e % 50;
            int rr = e / 50;
            int c = rr & 3; rr >>= 2;
            int dy = rr % 3, pl = rr / 3;
            int yy = y + dy - 1, zz = z - 1;
            s8v v = {0,0,0,0,0,0,0,0};
            if ((unsigned)yy < 48u && (unsigned)zz < 48u) {
                const unsigned short* src = (pl ? inLo : inHi) + inb
                    + ((size_t)((xx*48 + yy)*48 + zz)*32 + c*8);
                v = *(const s8v*)src;
            }
            *(s8v*)&sA[pl][dy][c][z*8] = v;
        }
        __syncthreads();
        for (int dy = 0; dy < 3; ++dy) {
            #pragma unroll
            for (int dz = 0; dz < 3; ++dz) {
                s8v Ah = *(const s8v*)&sA[0][dy][c4][(wv*16 + zr + dz)*8];
                s8v Al = *(const s8v*)&sA[1][dy][c4][(wv*16 + zr + dz)*8];
                int tap = (dx*3 + dy)*3 + dz;
                const s8v* wb = (const s8v*)(wp + (size_t)tap*2048);
                s8v Bh0 = wb[0*64 + lane];
                s8v Bl0 = wb[1*64 + lane];
                s8v Bh1 = wb[2*64 + lane];
                s8v Bl1 = wb[3*64 + lane];
                acc0 = __builtin_amdgcn_mfma_f32_16x16x32_bf16(Ah, Bh0, acc0, 0, 0, 0);
                acc1 = __builtin_amdgcn_mfma_f32_16x16x32_bf16(Ah, Bh1, acc1, 0, 0, 0);
                acc0 = __builtin_amdgcn_mfma_f32_16x16x32_bf16(Ah, Bl0, acc0, 0, 0, 0);
                acc1 = __builtin_amdgcn_mfma_f32_16x16x32_bf16(Ah, Bl1, acc1, 0, 0, 0);
                acc0 = __builtin_amdgcn_mfma_f32_16x16x32_bf16(Al, Bh0, acc0, 0, 0, 0);
                acc1 = __builtin_amdgcn_mfma_f32_16x16x32_bf16(Al, Bh1, acc1, 0, 0, 0);
            }
        }
    }

    // epilogue mask: m0 dilated by DIL for this row
    u64 om;
    if (DIL == 0) {
        om = m0[b*2304 + x*48 + y];
    } else {
        om = 0;
        for (int dx=-DIL; dx<=DIL; ++dx){ int xx=x+dx; if ((unsigned)xx >= 48u) continue;
          for (int dy=-DIL; dy<=DIL; ++dy){ int yy=y+dy; if ((unsigned)yy >= 48u) continue;
            u64 m = m0[b*2304 + xx*48 + yy];
            u64 d = m | (m<<1) | (m>>1);
            if (DIL == 2) d |= (m<<2) | (m>>2);
            om |= d;
          }}
        om &= (1ull<<48) - 1ull;
    }

    int co_l = lane & 15, rg = lane >> 4;
    if (MODE == 0) {
        #pragma unroll
        for (int half = 0; half < 2; ++half) {
            f4v a = half ? acc1 : acc0;
            #pragma unroll
            for (int reg = 0; reg < 4; ++reg) {
                int z = wv*16 + rg*4 + reg;
                float v = fmaxf(a[reg], 0.f);
                if (!((om >> z) & 1ull)) v = 0.f;
                unsigned hb = rne16(v);
                unsigned lb = rne16(v - bf2f(hb));
                size_t o = inb + ((size_t)((x*48 + y)*48 + z))*32 + half*16 + co_l;
                outHi[o] = (unsigned short)hb;
                outLo[o] = (unsigned short)lb;
            }
        }
    } else {
        int nb_ = imin(nout[b], MAXF);
        int rb = rowbase2[(b*48 + x)*48 + y];
        #pragma unroll
        for (int half = 0; half < 2; ++half) {
            f4v a = half ? acc1 : acc0;
            #pragma unroll
            for (int reg = 0; reg < 4; ++reg) {
                int z = wv*16 + rg*4 + reg;
                if ((om >> z) & 1ull) {
                    int rank = __popcll(om & ((1ull << z) - 1ull));
                    int slot = rb + rank;
                    if (slot >= 0 && slot < nb_)
                        outf[((size_t)(b*MAXF + slot))*32 + half*16 + co_l] = a[reg];
                }
            }
        }
    }
}

extern "C" void kernel_launch(void* const* d_in, const int* in_sizes, int n_in,
                              void* d_out, int out_size, void* d_ws, size_t ws_size,
                              hipStream_t stream)
{
    const float* feat   = (const float*)d_in[0];
    const int*   coords = (const int*)d_in[1];
    const float* w1 = (const float*)d_in[2];
    const float* w2 = (const float*)d_in[3];
    const float* w3 = (const float*)d_in[4];
    const float* w4 = (const float*)d_in[5];
    const float* w5 = (const float*)d_in[6];
    float* out = (float*)d_out;
    (void)in_sizes; (void)n_in; (void)out_size; (void)ws_size;

    char* ws = (char*)d_ws;
    size_t off = 0;
    auto carve = [&](size_t bytes)->char* { char* p = ws + off; off = align_up(off + bytes, 256); return p; };

    int*  winner   = (int*)carve((size_t)BB*VV*4);
    u64*  m0       = (u64*)carve((size_t)BB*2304*8);
    int*  nout     = (int*)carve(BB*4);
    int*  xl5      = (int*)carve(BB*4);
    int*  rowbase2 = (int*)carve(96*48*4);
    short* wpack   = (short*)carve((size_t)5*27*2048*2);
    unsigned short* gHi = (unsigned short*)carve((size_t)BB*VV*32*2);
    unsigned short* gLo = (unsigned short*)carve((size_t)BB*VV*32*2);
    unsigned short* aHi = (unsigned short*)carve((size_t)BB*VV*32*2);
    unsigned short* aLo = (unsigned short*)carve((size_t)BB*VV*32*2);
    unsigned short* bHi = (unsigned short*)carve((size_t)BB*VV*32*2);
    unsigned short* bLo = (unsigned short*)carve((size_t)BB*VV*32*2);

    hipMemsetAsync(winner, 0xFF, (size_t)BB*VV*4, stream);
    hipMemsetAsync(m0, 0, (size_t)BB*2304*8, stream);
    hipMemsetAsync(out, 0, (size_t)BB*MAXF*32*4, stream);

    k1_scatter_wpack<<<299, 192, 0, stream>>>(coords, w1, w2, w3, w4, w5, winner, m0, wpack);
    k2_stats<<<1, 1024, 0, stream>>>(m0, nout, xl5, rowbase2);
    k3_zero_scatter<<<BB*2304 + 209, 192, 0, stream>>>(coords, feat, winner, m0, xl5, gHi, gLo);

    const size_t LSZ = (size_t)27*2048;   // shorts per layer in wpack
    dim3 cgrid(48, 48, BB);
    conv_mfma_k<0,0><<<cgrid, 192, 0, stream>>>(gHi, gLo, wpack + 0*LSZ, m0, xl5, 4,
                                                aHi, aLo, nullptr, nullptr, nullptr);
    conv_mfma_k<0,0><<<cgrid, 192, 0, stream>>>(aHi, aLo, wpack + 1*LSZ, m0, xl5, 3,
                                                bHi, bLo, nullptr, nullptr, nullptr);
    conv_mfma_k<0,0><<<cgrid, 192, 0, stream>>>(bHi, bLo, wpack + 2*LSZ, m0, xl5, 2,
                                                aHi, aLo, nullptr, nullptr, nullptr);
    conv_mfma_k<0,1><<<cgrid, 192, 0, stream>>>(aHi, aLo, wpack + 3*LSZ, m0, xl5, 1,
                                                bHi, bLo, nullptr, nullptr, nullptr);
    conv_mfma_k<1,2><<<cgrid, 192, 0, stream>>>(bHi, bLo, wpack + 4*LSZ, m0, xl5, 0,
                                                nullptr, nullptr, rowbase2, nout, out);
}

// Round 11
// 177.191 us; speedup vs baseline: 5.1100x; 1.1385x over previous
//
#include <hip/hip_runtime.h>

typedef unsigned long long u64;
typedef __attribute__((ext_vector_type(8))) short s8v;
typedef __attribute__((ext_vector_type(4))) float f4v;

#define VV 110592            // 48^3
#define BB 2
#define NPTS 20000
#define MAXF 5000

static inline size_t align_up(size_t v, size_t a){ return (v + a - 1) & ~(a - 1); }

__device__ __forceinline__ int imin(int a, int b){ return a < b ? a : b; }

// round-to-nearest-even f32 -> bf16 bits
__device__ __forceinline__ unsigned rne16(float f){
    unsigned u = __float_as_uint(f);
    return (u + 0x7fffu + ((u >> 16) & 1u)) >> 16;
}
__device__ __forceinline__ float bf2f(unsigned h){ return __uint_as_float(h << 16); }

// ---------------- K1: scatter pass 1 + weight pack + d_out zero ----------------
// blocks [0,209): scatter; [209,299): pack 270 (layer,tap,half) groups; [299,313): zero d_out.
__global__ __launch_bounds__(192) void k1_scatter_wpack(
        const int* __restrict__ coords,
        const float* __restrict__ w1, const float* __restrict__ w2,
        const float* __restrict__ w3, const float* __restrict__ w4,
        const float* __restrict__ w5,
        int* __restrict__ winner, u64* __restrict__ m0, short* __restrict__ wpack,
        float* __restrict__ outf)
{
    int bid = blockIdx.x;
    if (bid < 209) {
        int t = bid*192 + threadIdx.x;
        if (t >= BB*NPTS) return;
        int b = t / NPTS, n = t - b*NPTS;
        const int* c = coords + (size_t)t*3;
        atomicMax(&winner[b*VV + (c[0]*48 + c[1])*48 + c[2]], n);   // init 0: 0 <= n ok
        atomicOr(&m0[b*2304 + c[0]*48 + c[1]], 1ull << c[2]);
    } else if (bid < 299) {
        int g = (bid - 209)*192 + threadIdx.x;    // 0..17279 = 270 groups * 64 lanes
        int lane = g & 63, wb = g >> 6;
        int layer = wb / 54; int r = wb % 54; int tap = r >> 1, half = r & 1;
        const float* w = layer==0?w1: layer==1?w2: layer==2?w3: layer==3?w4: w5;
        int cin = (layer == 0) ? 16 : 32;
        int n = half*16 + (lane & 15);
        s8v hv, lv;
        #pragma unroll
        for (int j = 0; j < 8; ++j) {
            int k = (lane >> 4)*8 + j;
            float v = (k < cin) ? w[((size_t)tap*cin + k)*32 + n] : 0.f;
            unsigned hb = rne16(v);
            hv[j] = (short)hb;
            lv[j] = (short)rne16(v - bf2f(hb));
        }
        size_t base = ((size_t)(layer*27 + tap)*2 + half)*2*512 + (size_t)lane*8;
        *(s8v*)&wpack[base] = hv;
        *(s8v*)&wpack[base + 512] = lv;
    } else {
        f4v zf = {0.f,0.f,0.f,0.f};
        for (int i = (bid-299)*192 + threadIdx.x; i < BB*MAXF*8; i += 14*192)
            *(f4v*)&outf[(size_t)i*4] = zf;
    }
}

// ---------------- K2: single-block stats via LDS separable dilation ----------------
// emits m1 (r=1), m2 (r=2), nout, rowbase2.
__global__ __launch_bounds__(1024) void k2_stats(const u64* __restrict__ m0,
        u64* __restrict__ m1, u64* __restrict__ m2,
        int* __restrict__ nout, int* __restrict__ rowbase2)
{
    __shared__ u64 ydil[BB*2304];
    __shared__ int cnt[BB*2304];
    __shared__ int sliceTot[96], sliceBase[96];
    const u64 M48 = (1ull<<48) - 1ull;
    int tid = threadIdx.x;

    // pass A (r=1): y/z dilation into LDS
    for (int rid = tid; rid < BB*2304; rid += 1024) {
        int b = rid / 2304, r = rid - b*2304, x = r / 48, y = r - x*48;
        u64 a = 0;
        for (int dy=-1; dy<=1; ++dy){ int yy=y+dy; if ((unsigned)yy>=48u) continue;
            u64 m = m0[(b*48 + x)*48 + yy]; a |= m | (m<<1) | (m>>1); }
        ydil[rid] = a;
    }
    __syncthreads();
    for (int rid = tid; rid < BB*2304; rid += 1024) {
        int b = rid / 2304, r = rid - b*2304, x = r / 48, y = r - x*48;
        u64 a = 0;
        for (int dx=-1; dx<=1; ++dx){ int xx=x+dx; if ((unsigned)xx>=48u) continue;
            a |= ydil[b*2304 + xx*48 + y]; }
        m1[rid] = a & M48;
    }
    __syncthreads();
    // pass B (r=2)
    for (int rid = tid; rid < BB*2304; rid += 1024) {
        int b = rid / 2304, r = rid - b*2304, x = r / 48, y = r - x*48;
        u64 a = 0;
        for (int dy=-2; dy<=2; ++dy){ int yy=y+dy; if ((unsigned)yy>=48u) continue;
            u64 m = m0[(b*48 + x)*48 + yy];
            a |= m | (m<<1) | (m>>1) | (m<<2) | (m>>2); }
        ydil[rid] = a;
    }
    __syncthreads();
    for (int rid = tid; rid < BB*2304; rid += 1024) {
        int b = rid / 2304, r = rid - b*2304, x = r / 48, y = r - x*48;
        u64 a = 0;
        for (int dx=-2; dx<=2; ++dx){ int xx=x+dx; if ((unsigned)xx>=48u) continue;
            a |= ydil[b*2304 + xx*48 + y]; }
        a &= M48;
        m2[rid] = a;
        cnt[rid] = __popcll(a);
    }
    __syncthreads();
    if (tid < 96) { int s = 0; for (int y=0;y<48;++y) s += cnt[tid*48+y]; sliceTot[tid] = s; }
    __syncthreads();
    if (tid < BB) {
        int b = tid;
        int tot = 0; for (int x=0;x<48;++x) tot += sliceTot[b*48+x];
        nout[b] = tot < MAXF ? tot : MAXF;
        int run = 0;
        for (int x=0;x<48;++x){ sliceBase[b*48+x] = run; run += sliceTot[b*48+x]; }
    }
    __syncthreads();
    if (tid < 96) {
        int run = sliceBase[tid];
        for (int y=0;y<48;++y){ rowbase2[tid*48+y] = run; run += cnt[tid*48+y]; }
    }
}

// ---------------- K3: cone-limited masked zero + winner feature scatter ----------------
__global__ __launch_bounds__(192) void k3_zero_scatter(
        const int* __restrict__ coords, const float* __restrict__ feat,
        const int* __restrict__ winner, const u64* __restrict__ m0,
        const int* __restrict__ rowbase2, const int* __restrict__ nout,
        unsigned short* __restrict__ gHi, unsigned short* __restrict__ gLo)
{
    int bid = blockIdx.x;
    if (bid < BB*2304) {
        int b = bid / 2304, r = bid - b*2304, x = r / 48, y = r - x*48;
        int clx = x-5; if (clx<0) clx=0;
        int cly = y-5; if (cly<0) cly=0;
        if (rowbase2[(b*48+clx)*48+cly] >= nout[b]) return;   // outside conv1's read cone
        u64 om = m0[b*2304 + x*48 + y];
        int i = threadIdx.x;                 // chunk 0..191, z = i>>2
        int z = i >> 2;
        if (!((om >> z) & 1ull)) {
            size_t base = ((size_t)b*VV + x*2304 + y*48) * 32 + (size_t)i*8;
            s8v z8 = {0,0,0,0,0,0,0,0};
            *(s8v*)&gHi[base] = z8;
            *(s8v*)&gLo[base] = z8;
        }
    } else {
        int t = (bid - BB*2304)*192 + threadIdx.x;
        if (t >= BB*NPTS) return;
        int b = t / NPTS, n = t - b*NPTS;
        const int* c = coords + (size_t)t*3;
        int gi = b*VV + (c[0]*48 + c[1])*48 + c[2];
        if (winner[gi] != n) return;
        const float* f = feat + (size_t)t*16;
        size_t base = (size_t)gi*32;
        #pragma unroll
        for (int ch = 0; ch < 2; ++ch) {
            s8v hv, lv;
            #pragma unroll
            for (int j = 0; j < 8; ++j) {
                float v = f[ch*8 + j];
                unsigned hb = rne16(v);
                hv[j] = (short)hb;
                lv[j] = (short)rne16(v - bf2f(hb));
            }
            *(s8v*)&gHi[base + ch*8] = hv;
            *(s8v*)&gLo[base + ch*8] = lv;
        }
    }
}

// ---------------- MFMA conv layer (proven body; cone skip; single-load mask) ----------------
// MODE 0: bf16 hi/lo planes with ReLU + mask.  MODE 1: gathered f32 -> d_out.
template<int MODE>
__global__ __launch_bounds__(192) void conv_mfma_k(
        const unsigned short* __restrict__ inHi, const unsigned short* __restrict__ inLo,
        const short* __restrict__ wp, const u64* __restrict__ mask,
        const int* __restrict__ rowbase2, const int* __restrict__ nout, int kskip,
        unsigned short* __restrict__ outHi, unsigned short* __restrict__ outLo,
        float* __restrict__ outf)
{
    int y = blockIdx.x, x = blockIdx.y, b = blockIdx.z;
    int nb_ = nout[b];
    int clx = x - kskip; if (clx < 0) clx = 0;
    int cly = y - kskip; if (cly < 0) cly = 0;
    if (rowbase2[(b*48 + clx)*48 + cly] >= nb_) return;   // outside the output cone

    __shared__ short sA[2][3][4][400];   // [plane][dy][cichunk][50 z * 8 bf16] = 19.2 KB
    int tid = threadIdx.x;
    int lane = tid & 63;
    int wv = tid >> 6;                   // z-tile 0..2
    int c4 = lane >> 4, zr = lane & 15;

    f4v acc0 = {0.f,0.f,0.f,0.f};
    f4v acc1 = {0.f,0.f,0.f,0.f};
    const size_t inb = (size_t)b*VV*32;

    for (int dx = 0; dx < 3; ++dx) {
        __syncthreads();
        int xx = x + dx - 1;
        if ((unsigned)xx >= 48u) continue;
        for (int e = tid; e < 1200; e += 192) {
            int z = e % 50;
            int rr = e / 50;
            int c = rr & 3; rr >>= 2;
            int dy = rr % 3, pl = rr / 3;
            int yy = y + dy - 1, zz = z - 1;
            s8v v = {0,0,0,0,0,0,0,0};
            if ((unsigned)yy < 48u && (unsigned)zz < 48u) {
                const unsigned short* src = (pl ? inLo : inHi) + inb
                    + ((size_t)((xx*48 + yy)*48 + zz)*32 + c*8);
                v = *(const s8v*)src;
            }
            *(s8v*)&sA[pl][dy][c][z*8] = v;
        }
        __syncthreads();
        for (int dy = 0; dy < 3; ++dy) {
            #pragma unroll
            for (int dz = 0; dz < 3; ++dz) {
                s8v Ah = *(const s8v*)&sA[0][dy][c4][(wv*16 + zr + dz)*8];
                s8v Al = *(const s8v*)&sA[1][dy][c4][(wv*16 + zr + dz)*8];
                int tap = (dx*3 + dy)*3 + dz;
                const s8v* wb = (const s8v*)(wp + (size_t)tap*2048);
                s8v Bh0 = wb[0*64 + lane];
                s8v Bl0 = wb[1*64 + lane];
                s8v Bh1 = wb[2*64 + lane];
                s8v Bl1 = wb[3*64 + lane];
                acc0 = __builtin_amdgcn_mfma_f32_16x16x32_bf16(Ah, Bh0, acc0, 0, 0, 0);
                acc1 = __builtin_amdgcn_mfma_f32_16x16x32_bf16(Ah, Bh1, acc1, 0, 0, 0);
                acc0 = __builtin_amdgcn_mfma_f32_16x16x32_bf16(Ah, Bl0, acc0, 0, 0, 0);
                acc1 = __builtin_amdgcn_mfma_f32_16x16x32_bf16(Ah, Bl1, acc1, 0, 0, 0);
                acc0 = __builtin_amdgcn_mfma_f32_16x16x32_bf16(Al, Bh0, acc0, 0, 0, 0);
                acc1 = __builtin_amdgcn_mfma_f32_16x16x32_bf16(Al, Bh1, acc1, 0, 0, 0);
            }
        }
    }

    u64 om = mask[b*2304 + x*48 + y];
    int co_l = lane & 15, rg = lane >> 4;
    if (MODE == 0) {
        #pragma unroll
        for (int half = 0; half < 2; ++half) {
            f4v a = half ? acc1 : acc0;
            #pragma unroll
            for (int reg = 0; reg < 4; ++reg) {
                int z = wv*16 + rg*4 + reg;
                float v = fmaxf(a[reg], 0.f);
                if (!((om >> z) & 1ull)) v = 0.f;
                unsigned hb = rne16(v);
                unsigned lb = rne16(v - bf2f(hb));
                size_t o = inb + ((size_t)((x*48 + y)*48 + z))*32 + half*16 + co_l;
                outHi[o] = (unsigned short)hb;
                outLo[o] = (unsigned short)lb;
            }
        }
    } else {
        int rb = rowbase2[(b*48 + x)*48 + y];
        #pragma unroll
        for (int half = 0; half < 2; ++half) {
            f4v a = half ? acc1 : acc0;
            #pragma unroll
            for (int reg = 0; reg < 4; ++reg) {
                int z = wv*16 + rg*4 + reg;
                if ((om >> z) & 1ull) {
                    int rank = __popcll(om & ((1ull << z) - 1ull));
                    int slot = rb + rank;
                    if (slot >= 0 && slot < nb_)
                        outf[((size_t)(b*MAXF + slot))*32 + half*16 + co_l] = a[reg];
                }
            }
        }
    }
}

extern "C" void kernel_launch(void* const* d_in, const int* in_sizes, int n_in,
                              void* d_out, int out_size, void* d_ws, size_t ws_size,
                              hipStream_t stream)
{
    const float* feat   = (const float*)d_in[0];
    const int*   coords = (const int*)d_in[1];
    const float* w1 = (const float*)d_in[2];
    const float* w2 = (const float*)d_in[3];
    const float* w3 = (const float*)d_in[4];
    const float* w4 = (const float*)d_in[5];
    const float* w5 = (const float*)d_in[6];
    float* out = (float*)d_out;
    (void)in_sizes; (void)n_in; (void)out_size; (void)ws_size;

    char* ws = (char*)d_ws;
    size_t off = 0;
    auto carve = [&](size_t bytes)->char* { char* p = ws + off; off = align_up(off + bytes, 256); return p; };

    int*  winner   = (int*)carve((size_t)BB*VV*4);       // contiguous with m0 (sizes 256-mult)
    u64*  m0       = (u64*)carve((size_t)BB*2304*8);
    u64*  m1       = (u64*)carve((size_t)BB*2304*8);
    u64*  m2       = (u64*)carve((size_t)BB*2304*8);
    int*  nout     = (int*)carve(BB*4);
    int*  rowbase2 = (int*)carve(96*48*4);
    short* wpack   = (short*)carve((size_t)5*27*2048*2);
    unsigned short* gHi = (unsigned short*)carve((size_t)BB*VV*32*2);
    unsigned short* gLo = (unsigned short*)carve((size_t)BB*VV*32*2);
    unsigned short* aHi = (unsigned short*)carve((size_t)BB*VV*32*2);
    unsigned short* aLo = (unsigned short*)carve((size_t)BB*VV*32*2);
    unsigned short* bHi = (unsigned short*)carve((size_t)BB*VV*32*2);
    unsigned short* bLo = (unsigned short*)carve((size_t)BB*VV*32*2);

    // single fill: winner (0-init valid for atomicMax) + m0 in one contiguous memset
    hipMemsetAsync(winner, 0, (size_t)BB*VV*4 + (size_t)BB*2304*8, stream);

    k1_scatter_wpack<<<313, 192, 0, stream>>>(coords, w1, w2, w3, w4, w5,
                                              winner, m0, wpack, out);
    k2_stats<<<1, 1024, 0, stream>>>(m0, m1, m2, nout, rowbase2);
    k3_zero_scatter<<<BB*2304 + 209, 192, 0, stream>>>(coords, feat, winner, m0,
                                                       rowbase2, nout, gHi, gLo);

    const size_t LSZ = (size_t)27*2048;   // shorts per layer in wpack
    dim3 cgrid(48, 48, BB);
    conv_mfma_k<0><<<cgrid, 192, 0, stream>>>(gHi, gLo, wpack + 0*LSZ, m0,
                                              rowbase2, nout, 4, aHi, aLo, nullptr);
    conv_mfma_k<0><<<cgrid, 192, 0, stream>>>(aHi, aLo, wpack + 1*LSZ, m0,
                                              rowbase2, nout, 3, bHi, bLo, nullptr);
    conv_mfma_k<0><<<cgrid, 192, 0, stream>>>(bHi, bLo, wpack + 2*LSZ, m0,
                                              rowbase2, nout, 2, aHi, aLo, nullptr);
    conv_mfma_k<0><<<cgrid, 192, 0, stream>>>(aHi, aLo, wpack + 3*LSZ, m1,
                                              rowbase2, nout, 1, bHi, bLo, nullptr);
    conv_mfma_k<1><<<cgrid, 192, 0, stream>>>(bHi, bLo, wpack + 4*LSZ, m2,
                                              rowbase2, nout, 0, nullptr, nullptr, out);
}